// Round 6
// baseline (190.600 us; speedup 1.0000x reference)
//
#include <hip/hip_runtime.h>

typedef float f32x4 __attribute__((ext_vector_type(4)));
typedef short short8 __attribute__((ext_vector_type(8)));
typedef short short4_t __attribute__((ext_vector_type(4)));

#define GLOAD_LDS16(gp, lp) \
  __builtin_amdgcn_global_load_lds((const __attribute__((address_space(1))) void*)(gp), \
                                   (__attribute__((address_space(3))) void*)(lp), 16, 0, 0)

__device__ __forceinline__ short f2bf(float f){
  unsigned u = __builtin_bit_cast(unsigned, f);
  u += 0x7fffu + ((u >> 16) & 1u);   // RNE, no NaN inputs here
  return (short)(u >> 16);
}

__device__ __forceinline__ float exp2_fast(float x){
  return __builtin_amdgcn_exp2f(x);  // v_exp_f32: 2^x
}

// ---------------- fp32 -> bf16 convert (vectorized) ----------------
__global__ void cvt_kernel(const float* __restrict__ x, short* __restrict__ xb, int n4){
  for (int i = blockIdx.x*blockDim.x + threadIdx.x; i < n4; i += gridDim.x*blockDim.x){
    f32x4 v = ((const f32x4*)x)[i];
    short4_t s;
    s[0]=f2bf(v[0]); s[1]=f2bf(v[1]); s[2]=f2bf(v[2]); s[3]=f2bf(v[3]);
    ((short4_t*)xb)[i] = s;
  }
}

// ------------- transpose+convert: w[K][N] fp32 -> wT[N][K] bf16 -------------
__global__ __launch_bounds__(256) void transpose_cvt_kernel(const float* __restrict__ w,
                                                            short* __restrict__ wT,
                                                            int K, int N){
  __shared__ float tile[32][33];
  int bn = blockIdx.x*32, bk = blockIdx.y*32;
  int tx = threadIdx.x & 31, ty = threadIdx.x >> 5;   // 256 threads: ty 0..7
  #pragma unroll
  for (int r=ty; r<32; r+=8) tile[r][tx] = w[(size_t)(bk+r)*N + bn + tx];
  __syncthreads();
  #pragma unroll
  for (int r=ty; r<32; r+=8) wT[(size_t)(bn+r)*K + bk + tx] = f2bf(tile[tx][r]);
}

// ---------------- 128x128 bf16 GEMM: C = A[M][K] * Bt[N][K]^T ----------------
// 256 threads = 4 waves (2x2), each wave 64x64 via 4x4 frags of 16x16x32.
// MODE 0: write fp32 C.  MODE 1: QKV epilogue -> q(prescaled, log2e folded)/k, v^T.
template<int MODE>
__global__ __launch_bounds__(256) void gemm128_kernel(
    const short* __restrict__ A, const short* __restrict__ Bt,
    float* __restrict__ Cf, short* __restrict__ qb_, short* __restrict__ kb_,
    short* __restrict__ vtb, int M, int N, int K)
{
  __shared__ short a_lds[128*64];
  __shared__ short b_lds[128*64];
  const int tid = threadIdx.x;
  const int lane = tid & 63;
  const int l15 = lane & 15, lg = lane >> 4;
  const int w  = tid >> 6;
  const int wr = w >> 1, wc = w & 1;
  const int m0 = blockIdx.x * 128, n0 = blockIdx.y * 128;

  f32x4 acc[4][4];
  #pragma unroll
  for (int i=0;i<4;i++)
    #pragma unroll
    for (int j=0;j<4;j++) acc[i][j] = (f32x4){0.f,0.f,0.f,0.f};

  for (int kt = 0; kt < K; kt += 64){
    __syncthreads();
    #pragma unroll
    for (int i=0;i<4;i++){
      int u = i*256 + tid;
      int row = u >> 3, cu = u & 7;
      int kl = ((cu ^ (row & 7)) << 3);
      GLOAD_LDS16(A + (size_t)(m0+row)*K + kt + kl, a_lds + (size_t)(i*256 + (tid & ~63))*8);
    }
    #pragma unroll
    for (int i=0;i<4;i++){
      int u = i*256 + tid;
      int row = u >> 3, cu = u & 7;
      int kl = ((cu ^ (row & 7)) << 3);
      GLOAD_LDS16(Bt + (size_t)(n0+row)*K + kt + kl, b_lds + (size_t)(i*256 + (tid & ~63))*8);
    }
    asm volatile("s_waitcnt vmcnt(0)" ::: "memory");
    __syncthreads();

    #pragma unroll
    for (int kk=0;kk<2;kk++){
      short8 af[4], bfr[4];
      #pragma unroll
      for (int mi=0;mi<4;mi++){
        int row = wr*64 + mi*16 + l15;
        int uu = ((kk*4 + lg) ^ (row & 7));
        af[mi] = *(const short8*)&a_lds[row*64 + uu*8];
      }
      #pragma unroll
      for (int ni=0;ni<4;ni++){
        int row = wc*64 + ni*16 + l15;
        int uu = ((kk*4 + lg) ^ (row & 7));
        bfr[ni] = *(const short8*)&b_lds[row*64 + uu*8];
      }
      #pragma unroll
      for (int mi=0;mi<4;mi++)
        #pragma unroll
        for (int ni=0;ni<4;ni++)
          acc[mi][ni] = __builtin_amdgcn_mfma_f32_16x16x32_bf16(af[mi], bfr[ni], acc[mi][ni], 0,0,0);
    }
  }

  // epilogue: D layout col = lane&15, row = (lane>>4)*4 + r  [verified m89/m91]
  #pragma unroll
  for (int mi=0;mi<4;mi++){
    #pragma unroll
    for (int ni=0;ni<4;ni++){
      int col = n0 + wc*64 + ni*16 + l15;
      #pragma unroll
      for (int r=0;r<4;r++){
        int rowg = m0 + wr*64 + mi*16 + lg*4 + r;
        float v = acc[mi][ni][r];
        if (MODE == 0){
          Cf[(size_t)rowg*N + col] = v;
        } else {
          int three = col >> 10, hh = (col >> 6) & 15, e = col & 63;
          int bb = rowg >> 11, t = rowg & 2047;
          int bh = bb*16 + hh;
          // Q pre-scale: 1/sqrt(64) * log2(e)  (softmax computed in base 2)
          if (three == 0)      qb_[((size_t)bh*2048 + t)*64 + e] = f2bf(v * (0.125f*1.44269504f));
          else if (three == 1) kb_[((size_t)bh*2048 + t)*64 + e] = f2bf(v);
          else                 vtb[((size_t)bh*64 + e)*2048 + t] = f2bf(v);          // V transposed
        }
      }
    }
  }
}

// ---------------- causal flash attention (double-buffered K/V pipeline) ----------------
// grid = bh(32) * qblocks(32), longest-first; 256 threads = 4 waves, wave owns 16 q-rows.
// Q pre-scaled by 0.125*log2e; K [bh][t][64]; V^T [bh][64][t]. KVBLK=64.
// Pipeline: raw s_barrier + counted vmcnt(4) so next tile's global_load_lds stays in
// flight across the barrier (T3/T4 minimum 2-phase recipe).
__global__ __launch_bounds__(256) void attn_kernel(
    const short* __restrict__ q, const short* __restrict__ kbuf,
    const short* __restrict__ vt, short* __restrict__ ob)
{
  __shared__ short k_lds[2][64*64];
  __shared__ short v_lds[2][64*64];       // [e][kv] (V already transposed in global)
  __shared__ short p_lds[4*16*72];        // per-wave P tile, stride 72

  const int tid = threadIdx.x, lane = tid & 63, w = tid >> 6;
  const int l15 = lane & 15, lg = lane >> 4;
  const int qb = 31 - (blockIdx.x & 31);  // longest blocks launch first
  const int bh = blockIdx.x >> 5;
  const int q0 = qb * 64;

  const short* qg = q + ((size_t)bh*2048 + q0 + w*16 + l15)*64;
  short8 qf[2];
  qf[0] = *(const short8*)(qg + lg*8);
  qf[1] = *(const short8*)(qg + 32 + lg*8);

  f32x4 o_acc[4];
  #pragma unroll
  for (int ct=0;ct<4;ct++) o_acc[ct] = (f32x4){0.f,0.f,0.f,0.f};
  float mreg[4], lreg[4];
  #pragma unroll
  for (int r=0;r<4;r++){ mreg[r] = -1e30f; lreg[r] = 0.f; }

  const short* kg = kbuf + (size_t)bh*2048*64;
  const short* vg = vt   + (size_t)bh*64*2048;
  short* pw_lds = p_lds + w*16*72;

  const int wbase = (tid & ~63)*8;   // wave-uniform LDS base (in shorts)

  auto issue = [&](int kv0, int buf){
    #pragma unroll
    for (int i=0;i<2;i++){
      int u = i*256 + tid;
      int row = u >> 3, cu = u & 7;
      int kl = ((cu ^ (row & 7)) << 3);
      GLOAD_LDS16(kg + (size_t)(kv0+row)*64 + kl, &k_lds[buf][i*2048 + wbase]);
    }
    #pragma unroll
    for (int i=0;i<2;i++){
      int u = i*256 + tid;
      int row = u >> 3, cu = u & 7;
      int kl = ((cu ^ (row & 7)) << 3);
      GLOAD_LDS16(vg + (size_t)row*2048 + kv0 + kl, &v_lds[buf][i*2048 + wbase]);
    }
  };

  const int n = qb + 1;
  issue(0, 0);

  for (int s = 0; s < n; s++){
    const int cur = s & 1;
    if (s + 1 < n){
      issue((s+1)*64, cur ^ 1);
      asm volatile("s_waitcnt vmcnt(4)" ::: "memory");  // tile s landed; s+1 in flight
    } else {
      asm volatile("s_waitcnt vmcnt(0)" ::: "memory");
    }
    __builtin_amdgcn_s_barrier();                        // all waves' tile-s data visible

    const short* kl_ = &k_lds[cur][0];
    const short* vl_ = &v_lds[cur][0];

    // S = Q K^T (Q pre-scaled, base-2). D rows = q-rows (lg*4+r), cols = kv (ct*16+l15).
    f32x4 sacc[4];
    #pragma unroll
    for (int ct=0;ct<4;ct++) sacc[ct] = (f32x4){0.f,0.f,0.f,0.f};
    #pragma unroll
    for (int kk=0;kk<2;kk++){
      #pragma unroll
      for (int ct=0;ct<4;ct++){
        int row = ct*16 + l15;
        int uu = ((kk*4 + lg) ^ (row & 7));
        short8 kf = *(const short8*)&kl_[row*64 + uu*8];
        sacc[ct] = __builtin_amdgcn_mfma_f32_16x16x32_bf16(qf[kk], kf, sacc[ct], 0,0,0);
      }
    }

    if (s == qb){   // diagonal tile: causal mask
      int lrow = w*16 + lg*4;
      #pragma unroll
      for (int ct=0;ct<4;ct++){
        int lcol = ct*16 + l15;
        #pragma unroll
        for (int r=0;r<4;r++)
          if (lcol > lrow + r) sacc[ct][r] = -1e30f;
      }
    }

    // online softmax in base-2 fp32. Row spread across 16 lanes x 4 ct.
    float mnew[4], alpha[4];
    #pragma unroll
    for (int r=0;r<4;r++){
      float mx = fmaxf(fmaxf(sacc[0][r], sacc[1][r]), fmaxf(sacc[2][r], sacc[3][r]));
      mx = fmaxf(mx, __shfl_xor(mx, 1));
      mx = fmaxf(mx, __shfl_xor(mx, 2));
      mx = fmaxf(mx, __shfl_xor(mx, 4));
      mx = fmaxf(mx, __shfl_xor(mx, 8));
      mnew[r] = fmaxf(mreg[r], mx);
      alpha[r] = exp2_fast(mreg[r] - mnew[r]);
      mreg[r] = mnew[r];
    }
    f32x4 p[4];
    #pragma unroll
    for (int ct=0;ct<4;ct++)
      #pragma unroll
      for (int r=0;r<4;r++)
        p[ct][r] = exp2_fast(sacc[ct][r] - mnew[r]);
    #pragma unroll
    for (int r=0;r<4;r++){
      float sum = p[0][r]+p[1][r]+p[2][r]+p[3][r];
      sum += __shfl_xor(sum,1); sum += __shfl_xor(sum,2);
      sum += __shfl_xor(sum,4); sum += __shfl_xor(sum,8);
      lreg[r] = lreg[r]*alpha[r] + sum;
      #pragma unroll
      for (int ct=0;ct<4;ct++) o_acc[ct][r] *= alpha[r];
    }

    // P -> per-wave LDS (bf16), then PV MFMA. Wave-private buffer: order via waitcnt.
    #pragma unroll
    for (int ct=0;ct<4;ct++)
      #pragma unroll
      for (int r=0;r<4;r++)
        pw_lds[(lg*4 + r)*72 + ct*16 + l15] = f2bf(p[ct][r]);
    asm volatile("s_waitcnt lgkmcnt(0)" ::: "memory");

    #pragma unroll
    for (int kh=0;kh<2;kh++){
      short8 pa = *(const short8*)&pw_lds[l15*72 + kh*32 + lg*8];
      #pragma unroll
      for (int ct=0;ct<4;ct++){
        int row = ct*16 + l15;
        int uu = ((kh*4 + lg) ^ (row & 7));
        short8 vf = *(const short8*)&vl_[row*64 + uu*8];
        o_acc[ct] = __builtin_amdgcn_mfma_f32_16x16x32_bf16(pa, vf, o_acc[ct], 0,0,0);
      }
    }

    __builtin_amdgcn_s_barrier();   // all reads of buf[cur] done before it is overwritten
  }

  // normalize + write O as bf16 row-major [b*t][h*64+e]
  int bb = bh >> 4, hh = bh & 15;
  #pragma unroll
  for (int r=0;r<4;r++){
    float inv = 1.0f / lreg[r];
    int t = q0 + w*16 + lg*4 + r;
    size_t base = ((size_t)(bb*2048 + t))*1024 + (size_t)hh*64;
    #pragma unroll
    for (int ct=0;ct<4;ct++)
      ob[base + ct*16 + l15] = f2bf(o_acc[ct][r] * inv);
  }
}

extern "C" void kernel_launch(void* const* d_in, const int* in_sizes, int n_in,
                              void* d_out, int out_size, void* d_ws, size_t ws_size,
                              hipStream_t stream) {
  const float* x     = (const float*)d_in[0];   // [2,2048,1024]
  const float* w_qkv = (const float*)d_in[1];   // [1024,3072]
  const float* w_out = (const float*)d_in[2];   // [1024,1024]
  float* out = (float*)d_out;                   // [2,2048,1024] fp32

  char* ws = (char*)d_ws;
  short* xb    = (short*)(ws);                    // 8 MB  [4096][1024] bf16
  short* wqkvT = (short*)(ws + (8u  << 20));      // 6 MB  [3072][1024] bf16
  short* woutT = (short*)(ws + (14u << 20));      // 2 MB  [1024][1024] bf16
  short* qbuf  = (short*)(ws + (16u << 20));      // 8 MB  [32][2048][64] bf16 (prescaled)
  short* kbuf  = (short*)(ws + (24u << 20));      // 8 MB  [32][2048][64] bf16
  short* vtbuf = (short*)(ws + (32u << 20));      // 8 MB  [32][64][2048] bf16 (V^T)
  short* obuf  = (short*)(ws + (40u << 20));      // 8 MB  [4096][1024] bf16

  cvt_kernel<<<2048, 256, 0, stream>>>(x, xb, (4096*1024)/4);
  transpose_cvt_kernel<<<dim3(96,32), 256, 0, stream>>>(w_qkv, wqkvT, 1024, 3072);
  transpose_cvt_kernel<<<dim3(32,32), 256, 0, stream>>>(w_out, woutT, 1024, 1024);

  gemm128_kernel<1><<<dim3(32,24), 256, 0, stream>>>(xb, wqkvT, nullptr,
                                                     qbuf, kbuf, vtbuf, 4096, 3072, 1024);
  attn_kernel<<<dim3(1024), 256, 0, stream>>>(qbuf, kbuf, vtbuf, obuf);
  gemm128_kernel<0><<<dim3(32,8), 256, 0, stream>>>(obuf, woutT, out,
                                                    nullptr, nullptr, nullptr, 4096, 1024, 1024);
}

// Round 7
// 119.349 us; speedup vs baseline: 1.5970x; 1.5970x over previous
//
#include <hip/hip_runtime.h>

typedef float f32x4 __attribute__((ext_vector_type(4)));
typedef short short8 __attribute__((ext_vector_type(8)));
typedef short short4_t __attribute__((ext_vector_type(4)));

#define GLOAD_LDS16(gp, lp) \
  __builtin_amdgcn_global_load_lds((const __attribute__((address_space(1))) void*)(gp), \
                                   (__attribute__((address_space(3))) void*)(lp), 16, 0, 0)

__device__ __forceinline__ short f2bf(float f){
  unsigned u = __builtin_bit_cast(unsigned, f);
  u += 0x7fffu + ((u >> 16) & 1u);   // RNE, no NaN inputs here
  return (short)(u >> 16);
}

__device__ __forceinline__ float exp2_fast(float x){
  return __builtin_amdgcn_exp2f(x);  // v_exp_f32: 2^x
}

// ---------------- fp32 -> bf16 convert (vectorized) ----------------
__global__ void cvt_kernel(const float* __restrict__ x, short* __restrict__ xb, int n4){
  for (int i = blockIdx.x*blockDim.x + threadIdx.x; i < n4; i += gridDim.x*blockDim.x){
    f32x4 v = ((const f32x4*)x)[i];
    short4_t s;
    s[0]=f2bf(v[0]); s[1]=f2bf(v[1]); s[2]=f2bf(v[2]); s[3]=f2bf(v[3]);
    ((short4_t*)xb)[i] = s;
  }
}

// ------------- transpose+convert: w[K][N] fp32 -> wT[N][K] bf16 -------------
__global__ __launch_bounds__(256) void transpose_cvt_kernel(const float* __restrict__ w,
                                                            short* __restrict__ wT,
                                                            int K, int N){
  __shared__ float tile[32][33];
  int bn = blockIdx.x*32, bk = blockIdx.y*32;
  int tx = threadIdx.x & 31, ty = threadIdx.x >> 5;   // 256 threads: ty 0..7
  #pragma unroll
  for (int r=ty; r<32; r+=8) tile[r][tx] = w[(size_t)(bk+r)*N + bn + tx];
  __syncthreads();
  #pragma unroll
  for (int r=ty; r<32; r+=8) wT[(size_t)(bn+r)*K + bk + tx] = f2bf(tile[tx][r]);
}

// ---------------- 128x128 bf16 GEMM: C = A[M][K] * Bt[N][K]^T ----------------
template<int MODE>
__global__ __launch_bounds__(256) void gemm128_kernel(
    const short* __restrict__ A, const short* __restrict__ Bt,
    float* __restrict__ Cf, short* __restrict__ qb_, short* __restrict__ kb_,
    short* __restrict__ vtb, int M, int N, int K)
{
  __shared__ short a_lds[128*64];
  __shared__ short b_lds[128*64];
  const int tid = threadIdx.x;
  const int lane = tid & 63;
  const int l15 = lane & 15, lg = lane >> 4;
  const int w  = tid >> 6;
  const int wr = w >> 1, wc = w & 1;
  const int m0 = blockIdx.x * 128, n0 = blockIdx.y * 128;

  f32x4 acc[4][4];
  #pragma unroll
  for (int i=0;i<4;i++)
    #pragma unroll
    for (int j=0;j<4;j++) acc[i][j] = (f32x4){0.f,0.f,0.f,0.f};

  for (int kt = 0; kt < K; kt += 64){
    __syncthreads();
    #pragma unroll
    for (int i=0;i<4;i++){
      int u = i*256 + tid;
      int row = u >> 3, cu = u & 7;
      int kl = ((cu ^ (row & 7)) << 3);
      GLOAD_LDS16(A + (size_t)(m0+row)*K + kt + kl, a_lds + (size_t)(i*256 + (tid & ~63))*8);
    }
    #pragma unroll
    for (int i=0;i<4;i++){
      int u = i*256 + tid;
      int row = u >> 3, cu = u & 7;
      int kl = ((cu ^ (row & 7)) << 3);
      GLOAD_LDS16(Bt + (size_t)(n0+row)*K + kt + kl, b_lds + (size_t)(i*256 + (tid & ~63))*8);
    }
    asm volatile("s_waitcnt vmcnt(0)" ::: "memory");
    __syncthreads();

    #pragma unroll
    for (int kk=0;kk<2;kk++){
      short8 af[4], bfr[4];
      #pragma unroll
      for (int mi=0;mi<4;mi++){
        int row = wr*64 + mi*16 + l15;
        int uu = ((kk*4 + lg) ^ (row & 7));
        af[mi] = *(const short8*)&a_lds[row*64 + uu*8];
      }
      #pragma unroll
      for (int ni=0;ni<4;ni++){
        int row = wc*64 + ni*16 + l15;
        int uu = ((kk*4 + lg) ^ (row & 7));
        bfr[ni] = *(const short8*)&b_lds[row*64 + uu*8];
      }
      #pragma unroll
      for (int mi=0;mi<4;mi++)
        #pragma unroll
        for (int ni=0;ni<4;ni++)
          acc[mi][ni] = __builtin_amdgcn_mfma_f32_16x16x32_bf16(af[mi], bfr[ni], acc[mi][ni], 0,0,0);
    }
  }

  // epilogue: D layout col = lane&15, row = (lane>>4)*4 + r  [verified m89/m91]
  #pragma unroll
  for (int mi=0;mi<4;mi++){
    #pragma unroll
    for (int ni=0;ni<4;ni++){
      int col = n0 + wc*64 + ni*16 + l15;
      #pragma unroll
      for (int r=0;r<4;r++){
        int rowg = m0 + wr*64 + mi*16 + lg*4 + r;
        float v = acc[mi][ni][r];
        if (MODE == 0){
          Cf[(size_t)rowg*N + col] = v;
        } else {
          int three = col >> 10, hh = (col >> 6) & 15, e = col & 63;
          int bb = rowg >> 11, t = rowg & 2047;
          int bh = bb*16 + hh;
          // Q pre-scale: 1/sqrt(64) * log2(e)  (softmax computed in base 2)
          if (three == 0)      qb_[((size_t)bh*2048 + t)*64 + e] = f2bf(v * (0.125f*1.44269504f));
          else if (three == 1) kb_[((size_t)bh*2048 + t)*64 + e] = f2bf(v);
          else                 vtb[((size_t)bh*64 + e)*2048 + t] = f2bf(v);          // V transposed
        }
      }
    }
  }
}

// ---------------- causal flash attention ----------------
// grid: qb-major (long blocks dispatch first, all heads), bh = blockIdx&31.
// 256 threads = 4 waves, wave owns 16 q-rows. Q pre-scaled by 0.125*log2e.
// SWAPPED QK^T: sacc = mfma(K, Q) = S^T, so lane (l15) holds 16 S values of ONE
// q-row -> row reduce = in-lane fmax/add + 2 shuffles (was 4-deep chain x4 rows).
__global__ __launch_bounds__(256) void attn_kernel(
    const short* __restrict__ q, const short* __restrict__ kbuf,
    const short* __restrict__ vt, short* __restrict__ ob)
{
  __shared__ short k_lds[2][64*64];
  __shared__ short v_lds[2][64*64];       // [e][kv] (V already transposed in global)
  __shared__ short p_lds[4*16*72];        // per-wave P tile [q16][kv64], stride 72 (144B = 9*16 aligned)

  const int tid = threadIdx.x, lane = tid & 63, w = tid >> 6;
  const int l15 = lane & 15, lg = lane >> 4;
  const int qb = 31 - (blockIdx.x >> 5);  // qb-major: longest blocks first, all bh
  const int bh = blockIdx.x & 31;         // XCD = blockIdx%8 -> 4 heads per XCD L2
  const int q0 = qb * 64;

  const short* qg = q + ((size_t)bh*2048 + q0 + w*16 + l15)*64;
  short8 qf[2];
  qf[0] = *(const short8*)(qg + lg*8);
  qf[1] = *(const short8*)(qg + 32 + lg*8);

  f32x4 o_acc[4];
  #pragma unroll
  for (int ct=0;ct<4;ct++) o_acc[ct] = (f32x4){0.f,0.f,0.f,0.f};
  float mreg = -1e30f, lreg = 0.f;        // per-lane: this lane's q-row (q = w*16 + l15)

  const short* kg = kbuf + (size_t)bh*2048*64;
  const short* vg = vt   + (size_t)bh*64*2048;
  short* pw_lds = p_lds + w*16*72;

  const int wbase = (tid & ~63)*8;   // wave-uniform LDS base (in shorts)

  auto issue = [&](int kv0, int buf){
    #pragma unroll
    for (int i=0;i<2;i++){
      int u = i*256 + tid;
      int row = u >> 3, cu = u & 7;
      int kl = ((cu ^ (row & 7)) << 3);
      GLOAD_LDS16(kg + (size_t)(kv0+row)*64 + kl, &k_lds[buf][i*2048 + wbase]);
    }
    #pragma unroll
    for (int i=0;i<2;i++){
      int u = i*256 + tid;
      int row = u >> 3, cu = u & 7;
      int kl = ((cu ^ (row & 7)) << 3);
      GLOAD_LDS16(vg + (size_t)row*2048 + kv0 + kl, &v_lds[buf][i*2048 + wbase]);
    }
  };

  const int n = qb + 1;
  issue(0, 0);

  for (int s = 0; s < n; s++){
    const int cur = s & 1;
    if (s + 1 < n){
      issue((s+1)*64, cur ^ 1);
      asm volatile("s_waitcnt vmcnt(4)" ::: "memory");  // tile s landed; s+1 in flight
    } else {
      asm volatile("s_waitcnt vmcnt(0)" ::: "memory");
    }
    __builtin_amdgcn_s_barrier();                        // all waves' tile-s data visible

    const short* kl_ = &k_lds[cur][0];
    const short* vl_ = &v_lds[cur][0];

    // S^T = K Q^T (swapped). Lane holds sacc[ct][r] = S[kv = ct*16+lg*4+r][q = l15].
    f32x4 sacc[4];
    #pragma unroll
    for (int ct=0;ct<4;ct++) sacc[ct] = (f32x4){0.f,0.f,0.f,0.f};
    #pragma unroll
    for (int kk=0;kk<2;kk++){
      #pragma unroll
      for (int ct=0;ct<4;ct++){
        int row = ct*16 + l15;
        int uu = ((kk*4 + lg) ^ (row & 7));
        short8 kf = *(const short8*)&kl_[row*64 + uu*8];
        sacc[ct] = __builtin_amdgcn_mfma_f32_16x16x32_bf16(kf, qf[kk], sacc[ct], 0,0,0);
      }
    }

    if (s == qb){   // diagonal tile: mask kv_local > q_local
      int qloc = w*16 + l15;
      #pragma unroll
      for (int ct=0;ct<4;ct++){
        #pragma unroll
        for (int r=0;r<4;r++)
          if (ct*16 + lg*4 + r > qloc) sacc[ct][r] = -1e30f;
      }
    }

    // online softmax (base-2): one q-row per lane, 16 values in-register.
    float mx = -1e30f;
    #pragma unroll
    for (int ct=0;ct<4;ct++)
      #pragma unroll
      for (int r=0;r<4;r++) mx = fmaxf(mx, sacc[ct][r]);
    mx = fmaxf(mx, __shfl_xor(mx, 16));
    mx = fmaxf(mx, __shfl_xor(mx, 32));
    float mnew = fmaxf(mreg, mx);
    float alpha = exp2_fast(mreg - mnew);
    mreg = mnew;

    f32x4 p[4];
    float sum = 0.f;
    #pragma unroll
    for (int ct=0;ct<4;ct++)
      #pragma unroll
      for (int r=0;r<4;r++){
        p[ct][r] = exp2_fast(sacc[ct][r] - mnew);
        sum += p[ct][r];
      }
    sum += __shfl_xor(sum, 16);
    sum += __shfl_xor(sum, 32);
    lreg = lreg*alpha + sum;

    // redistribute alpha to o_acc row layout (o_acc row q = lg*4 + r)
    float alphaRow[4];
    #pragma unroll
    for (int r=0;r<4;r++) alphaRow[r] = __shfl(alpha, lg*4 + r);
    #pragma unroll
    for (int ct=0;ct<4;ct++)
      #pragma unroll
      for (int r=0;r<4;r++) o_acc[ct][r] *= alphaRow[r];

    // P -> per-wave LDS: lane writes its q-row (l15) kv-slice as packed bf16x4.
    #pragma unroll
    for (int ct=0;ct<4;ct++){
      short4_t s4;
      #pragma unroll
      for (int r=0;r<4;r++) s4[r] = f2bf(p[ct][r]);
      *(short4_t*)&pw_lds[l15*72 + ct*16 + lg*4] = s4;
    }
    asm volatile("s_waitcnt lgkmcnt(0)" ::: "memory");

    #pragma unroll
    for (int kh=0;kh<2;kh++){
      short8 pa = *(const short8*)&pw_lds[l15*72 + kh*32 + lg*8];
      #pragma unroll
      for (int ct=0;ct<4;ct++){
        int row = ct*16 + l15;
        int uu = ((kh*4 + lg) ^ (row & 7));
        short8 vf = *(const short8*)&vl_[row*64 + uu*8];
        o_acc[ct] = __builtin_amdgcn_mfma_f32_16x16x32_bf16(pa, vf, o_acc[ct], 0,0,0);
      }
    }

    __builtin_amdgcn_s_barrier();   // all reads of buf[cur] done before it is overwritten
  }

  // normalize + write O as bf16 row-major [b*t][h*64+e]. o_acc row q = lg*4+r;
  // lreg lives at lane l15 == q -> fetch via shuffle.
  int bb = bh >> 4, hh = bh & 15;
  float lfin[4];
  #pragma unroll
  for (int r=0;r<4;r++) lfin[r] = __shfl(lreg, lg*4 + r);
  #pragma unroll
  for (int r=0;r<4;r++){
    float inv = 1.0f / lfin[r];
    int t = q0 + w*16 + lg*4 + r;
    size_t base = ((size_t)(bb*2048 + t))*1024 + (size_t)hh*64;
    #pragma unroll
    for (int ct=0;ct<4;ct++)
      ob[base + ct*16 + l15] = f2bf(o_acc[ct][r] * inv);
  }
}

extern "C" void kernel_launch(void* const* d_in, const int* in_sizes, int n_in,
                              void* d_out, int out_size, void* d_ws, size_t ws_size,
                              hipStream_t stream) {
  const float* x     = (const float*)d_in[0];   // [2,2048,1024]
  const float* w_qkv = (const float*)d_in[1];   // [1024,3072]
  const float* w_out = (const float*)d_in[2];   // [1024,1024]
  float* out = (float*)d_out;                   // [2,2048,1024] fp32

  char* ws = (char*)d_ws;
  short* xb    = (short*)(ws);                    // 8 MB  [4096][1024] bf16
  short* wqkvT = (short*)(ws + (8u  << 20));      // 6 MB  [3072][1024] bf16
  short* woutT = (short*)(ws + (14u << 20));      // 2 MB  [1024][1024] bf16
  short* qbuf  = (short*)(ws + (16u << 20));      // 8 MB  [32][2048][64] bf16 (prescaled)
  short* kbuf  = (short*)(ws + (24u << 20));      // 8 MB  [32][2048][64] bf16
  short* vtbuf = (short*)(ws + (32u << 20));      // 8 MB  [32][64][2048] bf16 (V^T)
  short* obuf  = (short*)(ws + (40u << 20));      // 8 MB  [4096][1024] bf16

  cvt_kernel<<<2048, 256, 0, stream>>>(x, xb, (4096*1024)/4);
  transpose_cvt_kernel<<<dim3(96,32), 256, 0, stream>>>(w_qkv, wqkvT, 1024, 3072);
  transpose_cvt_kernel<<<dim3(32,32), 256, 0, stream>>>(w_out, woutT, 1024, 1024);

  gemm128_kernel<1><<<dim3(32,24), 256, 0, stream>>>(xb, wqkvT, nullptr,
                                                     qbuf, kbuf, vtbuf, 4096, 3072, 1024);
  attn_kernel<<<dim3(1024), 256, 0, stream>>>(qbuf, kbuf, vtbuf, obuf);
  gemm128_kernel<0><<<dim3(32,8), 256, 0, stream>>>(obuf, woutT, out,
                                                    nullptr, nullptr, nullptr, 4096, 1024, 1024);
}

// Round 8
// 118.828 us; speedup vs baseline: 1.6040x; 1.0044x over previous
//
#include <hip/hip_runtime.h>

typedef float f32x4 __attribute__((ext_vector_type(4)));
typedef short short8 __attribute__((ext_vector_type(8)));
typedef short short4_t __attribute__((ext_vector_type(4)));

#define GLOAD_LDS16(gp, lp) \
  __builtin_amdgcn_global_load_lds((const __attribute__((address_space(1))) void*)(gp), \
                                   (__attribute__((address_space(3))) void*)(lp), 16, 0, 0)

__device__ __forceinline__ short f2bf(float f){
  unsigned u = __builtin_bit_cast(unsigned, f);
  u += 0x7fffu + ((u >> 16) & 1u);   // RNE, no NaN inputs here
  return (short)(u >> 16);
}

__device__ __forceinline__ float exp2_fast(float x){
  return __builtin_amdgcn_exp2f(x);  // v_exp_f32: 2^x
}

// ---------------- fp32 -> bf16 convert (vectorized) ----------------
__global__ void cvt_kernel(const float* __restrict__ x, short* __restrict__ xb, int n4){
  for (int i = blockIdx.x*blockDim.x + threadIdx.x; i < n4; i += gridDim.x*blockDim.x){
    f32x4 v = ((const f32x4*)x)[i];
    short4_t s;
    s[0]=f2bf(v[0]); s[1]=f2bf(v[1]); s[2]=f2bf(v[2]); s[3]=f2bf(v[3]);
    ((short4_t*)xb)[i] = s;
  }
}

// ------------- transpose+convert: w[K][N] fp32 -> wT[N][K] bf16 -------------
__global__ __launch_bounds__(256) void transpose_cvt_kernel(const float* __restrict__ w,
                                                            short* __restrict__ wT,
                                                            int K, int N){
  __shared__ float tile[32][33];
  int bn = blockIdx.x*32, bk = blockIdx.y*32;
  int tx = threadIdx.x & 31, ty = threadIdx.x >> 5;   // 256 threads: ty 0..7
  #pragma unroll
  for (int r=ty; r<32; r+=8) tile[r][tx] = w[(size_t)(bk+r)*N + bn + tx];
  __syncthreads();
  #pragma unroll
  for (int r=ty; r<32; r+=8) wT[(size_t)(bn+r)*K + bk + tx] = f2bf(tile[tx][r]);
}

// ---------------- 128x128 bf16 GEMM: C = A[M][K] * Bt[N][K]^T ----------------
template<int MODE>
__global__ __launch_bounds__(256) void gemm128_kernel(
    const short* __restrict__ A, const short* __restrict__ Bt,
    float* __restrict__ Cf, short* __restrict__ qb_, short* __restrict__ kb_,
    short* __restrict__ vtb, int M, int N, int K)
{
  __shared__ short a_lds[128*64];
  __shared__ short b_lds[128*64];
  const int tid = threadIdx.x;
  const int lane = tid & 63;
  const int l15 = lane & 15, lg = lane >> 4;
  const int w  = tid >> 6;
  const int wr = w >> 1, wc = w & 1;
  const int m0 = blockIdx.x * 128, n0 = blockIdx.y * 128;

  f32x4 acc[4][4];
  #pragma unroll
  for (int i=0;i<4;i++)
    #pragma unroll
    for (int j=0;j<4;j++) acc[i][j] = (f32x4){0.f,0.f,0.f,0.f};

  for (int kt = 0; kt < K; kt += 64){
    __syncthreads();
    #pragma unroll
    for (int i=0;i<4;i++){
      int u = i*256 + tid;
      int row = u >> 3, cu = u & 7;
      int kl = ((cu ^ (row & 7)) << 3);
      GLOAD_LDS16(A + (size_t)(m0+row)*K + kt + kl, a_lds + (size_t)(i*256 + (tid & ~63))*8);
    }
    #pragma unroll
    for (int i=0;i<4;i++){
      int u = i*256 + tid;
      int row = u >> 3, cu = u & 7;
      int kl = ((cu ^ (row & 7)) << 3);
      GLOAD_LDS16(Bt + (size_t)(n0+row)*K + kt + kl, b_lds + (size_t)(i*256 + (tid & ~63))*8);
    }
    asm volatile("s_waitcnt vmcnt(0)" ::: "memory");
    __syncthreads();

    #pragma unroll
    for (int kk=0;kk<2;kk++){
      short8 af[4], bfr[4];
      #pragma unroll
      for (int mi=0;mi<4;mi++){
        int row = wr*64 + mi*16 + l15;
        int uu = ((kk*4 + lg) ^ (row & 7));
        af[mi] = *(const short8*)&a_lds[row*64 + uu*8];
      }
      #pragma unroll
      for (int ni=0;ni<4;ni++){
        int row = wc*64 + ni*16 + l15;
        int uu = ((kk*4 + lg) ^ (row & 7));
        bfr[ni] = *(const short8*)&b_lds[row*64 + uu*8];
      }
      #pragma unroll
      for (int mi=0;mi<4;mi++)
        #pragma unroll
        for (int ni=0;ni<4;ni++)
          acc[mi][ni] = __builtin_amdgcn_mfma_f32_16x16x32_bf16(af[mi], bfr[ni], acc[mi][ni], 0,0,0);
    }
  }

  // epilogue: D layout col = lane&15, row = (lane>>4)*4 + r  [verified m89/m91]
  #pragma unroll
  for (int mi=0;mi<4;mi++){
    #pragma unroll
    for (int ni=0;ni<4;ni++){
      int col = n0 + wc*64 + ni*16 + l15;
      #pragma unroll
      for (int r=0;r<4;r++){
        int rowg = m0 + wr*64 + mi*16 + lg*4 + r;
        float v = acc[mi][ni][r];
        if (MODE == 0){
          Cf[(size_t)rowg*N + col] = v;
        } else {
          int three = col >> 10, hh = (col >> 6) & 15, e = col & 63;
          int bb = rowg >> 11, t = rowg & 2047;
          int bh = bb*16 + hh;
          // Q pre-scale: 1/sqrt(64) * log2(e)  (softmax computed in base 2)
          if (three == 0)      qb_[((size_t)bh*2048 + t)*64 + e] = f2bf(v * (0.125f*1.44269504f));
          else if (three == 1) kb_[((size_t)bh*2048 + t)*64 + e] = f2bf(v);
          else                 vtb[((size_t)bh*64 + e)*2048 + t] = f2bf(v);          // V transposed
        }
      }
    }
  }
}

// ---------------- causal flash attention ----------------
// 512 threads = 8 waves, QBLK=128 (wave owns 16 q-rows), KVBLK=64, dbuf + vmcnt(2).
// qb pairing: blocks bid and bid+256 land on same CU; qb chosen so their tile
// counts sum to a constant 34 (load balance). Swapped QK^T (lane = one q-row).
__global__ __launch_bounds__(512) void attn_kernel(
    const short* __restrict__ q, const short* __restrict__ kbuf,
    const short* __restrict__ vt, short* __restrict__ ob)
{
  __shared__ short k_lds[2][64*64];
  __shared__ short v_lds[2][64*64];       // [e][kv] (V already transposed in global)
  __shared__ short p_lds[8*16*72];        // per-wave P tile [q16][kv64], stride 72

  const int tid = threadIdx.x, lane = tid & 63, w = tid >> 6;   // w 0..7
  const int l15 = lane & 15, lg = lane >> 4;
  const int qi = blockIdx.x >> 5;
  const int qb = (qi < 8) ? (15 - qi) : (qi - 8);   // pair sums constant
  const int bh = blockIdx.x & 31;
  const int q0 = qb * 128;

  const short* qg = q + ((size_t)bh*2048 + q0 + w*16 + l15)*64;
  short8 qf[2];
  qf[0] = *(const short8*)(qg + lg*8);
  qf[1] = *(const short8*)(qg + 32 + lg*8);

  f32x4 o_acc[4];
  #pragma unroll
  for (int ct=0;ct<4;ct++) o_acc[ct] = (f32x4){0.f,0.f,0.f,0.f};
  float mreg = -1e30f, lreg = 0.f;        // per-lane: q-row = w*16 + l15

  // hoisted LDS read byte-offsets (identical pattern for K and V tiles)
  int rdo[2][4];
  #pragma unroll
  for (int kk=0;kk<2;kk++)
    #pragma unroll
    for (int ct=0;ct<4;ct++){
      int row = ct*16 + l15;
      int uu = (kk*4 + lg) ^ (row & 7);
      rdo[kk][ct] = (row*64 + uu*8)*2;
    }

  // per-lane pre-swizzled global pointers; advance by constant per tile
  const int grow = tid >> 3, gcu = tid & 7;
  const int gkl = ((gcu ^ (grow & 7)) << 3);
  const short* kp = kbuf + (size_t)bh*2048*64 + (size_t)grow*64   + gkl;  // +4096/tile
  const short* vp = vt   + (size_t)bh*64*2048 + (size_t)grow*2048 + gkl;  // +64/tile
  const int wbase = (tid & ~63)*8;   // wave-uniform LDS dest base (shorts)

  char* pw = (char*)(p_lds + w*16*72);
  const int pwo = (l15*72 + lg*4)*2;   // P write byte offset (+ct*32)
  const int pro = (l15*72 + lg*8)*2;   // P read  byte offset (+kh*64)

  const int n = 2*qb + 2;
  GLOAD_LDS16(kp, &k_lds[0][wbase]); kp += 4096;
  GLOAD_LDS16(vp, &v_lds[0][wbase]); vp += 64;

  for (int s = 0; s < n; s++){
    const int cur = s & 1;
    if (s + 1 < n){
      GLOAD_LDS16(kp, &k_lds[cur^1][wbase]); kp += 4096;
      GLOAD_LDS16(vp, &v_lds[cur^1][wbase]); vp += 64;
      asm volatile("s_waitcnt vmcnt(2)" ::: "memory");  // tile s landed; s+1 in flight
    } else {
      asm volatile("s_waitcnt vmcnt(0)" ::: "memory");
    }
    __builtin_amdgcn_s_barrier();

    const char* kl_ = (const char*)&k_lds[cur][0];
    const char* vl_ = (const char*)&v_lds[cur][0];

    // S^T = K Q^T. Lane holds sacc[ct][r] = S[kv = ct*16+lg*4+r][q = l15].
    f32x4 sacc[4];
    #pragma unroll
    for (int ct=0;ct<4;ct++) sacc[ct] = (f32x4){0.f,0.f,0.f,0.f};
    #pragma unroll
    for (int kk=0;kk<2;kk++){
      #pragma unroll
      for (int ct=0;ct<4;ct++){
        short8 kf = *(const short8*)(kl_ + rdo[kk][ct]);
        sacc[ct] = __builtin_amdgcn_mfma_f32_16x16x32_bf16(kf, qf[kk], sacc[ct], 0,0,0);
      }
    }

    if (s >= 2*qb){   // last two tiles: causal mask (d = 0 or 1)
      int d = s - 2*qb;
      int qloc = w*16 + l15;
      #pragma unroll
      for (int ct=0;ct<4;ct++){
        #pragma unroll
        for (int r=0;r<4;r++)
          if (d*64 + ct*16 + lg*4 + r > qloc) sacc[ct][r] = -1e30f;
      }
    }

    // online softmax (base-2): one q-row per lane, 16 values in-register (max tree).
    float m01 = fmaxf(fmaxf(sacc[0][0], sacc[0][1]), fmaxf(sacc[0][2], sacc[0][3]));
    float m23 = fmaxf(fmaxf(sacc[1][0], sacc[1][1]), fmaxf(sacc[1][2], sacc[1][3]));
    float m45 = fmaxf(fmaxf(sacc[2][0], sacc[2][1]), fmaxf(sacc[2][2], sacc[2][3]));
    float m67 = fmaxf(fmaxf(sacc[3][0], sacc[3][1]), fmaxf(sacc[3][2], sacc[3][3]));
    float mx = fmaxf(fmaxf(m01, m23), fmaxf(m45, m67));
    mx = fmaxf(mx, __shfl_xor(mx, 16));
    mx = fmaxf(mx, __shfl_xor(mx, 32));
    float mnew = fmaxf(mreg, mx);
    float alpha = exp2_fast(mreg - mnew);
    mreg = mnew;

    f32x4 p[4];
    float sum = 0.f;
    #pragma unroll
    for (int ct=0;ct<4;ct++)
      #pragma unroll
      for (int r=0;r<4;r++){
        p[ct][r] = exp2_fast(sacc[ct][r] - mnew);
        sum += p[ct][r];
      }
    sum += __shfl_xor(sum, 16);
    sum += __shfl_xor(sum, 32);
    lreg = lreg*alpha + sum;

    float alphaRow[4];
    #pragma unroll
    for (int r=0;r<4;r++) alphaRow[r] = __shfl(alpha, lg*4 + r);
    #pragma unroll
    for (int ct=0;ct<4;ct++)
      #pragma unroll
      for (int r=0;r<4;r++) o_acc[ct][r] *= alphaRow[r];

    // P -> per-wave LDS via v_cvt_pk_bf16_f32 (2 f32 -> packed 2xbf16).
    #pragma unroll
    for (int ct=0;ct<4;ct++){
      uint2 pk;
      asm("v_cvt_pk_bf16_f32 %0, %1, %2" : "=v"(pk.x) : "v"(p[ct][0]), "v"(p[ct][1]));
      asm("v_cvt_pk_bf16_f32 %0, %1, %2" : "=v"(pk.y) : "v"(p[ct][2]), "v"(p[ct][3]));
      *(uint2*)(pw + pwo + ct*32) = pk;
    }
    asm volatile("s_waitcnt lgkmcnt(0)" ::: "memory");

    #pragma unroll
    for (int kh=0;kh<2;kh++){
      short8 pa = *(const short8*)(pw + pro + kh*64);
      #pragma unroll
      for (int ct=0;ct<4;ct++){
        short8 vf = *(const short8*)(vl_ + rdo[kh][ct]);
        o_acc[ct] = __builtin_amdgcn_mfma_f32_16x16x32_bf16(pa, vf, o_acc[ct], 0,0,0);
      }
    }

    __builtin_amdgcn_s_barrier();   // all reads of buf[cur] done before overwrite
  }

  // normalize + write O as bf16 row-major [b*t][h*64+e]
  int bb = bh >> 4, hh = bh & 15;
  float lfin[4];
  #pragma unroll
  for (int r=0;r<4;r++) lfin[r] = __shfl(lreg, lg*4 + r);
  #pragma unroll
  for (int r=0;r<4;r++){
    float inv = 1.0f / lfin[r];
    int t = q0 + w*16 + lg*4 + r;
    size_t base = ((size_t)(bb*2048 + t))*1024 + (size_t)hh*64;
    #pragma unroll
    for (int ct=0;ct<4;ct++)
      ob[base + ct*16 + l15] = f2bf(o_acc[ct][r] * inv);
  }
}

extern "C" void kernel_launch(void* const* d_in, const int* in_sizes, int n_in,
                              void* d_out, int out_size, void* d_ws, size_t ws_size,
                              hipStream_t stream) {
  const float* x     = (const float*)d_in[0];   // [2,2048,1024]
  const float* w_qkv = (const float*)d_in[1];   // [1024,3072]
  const float* w_out = (const float*)d_in[2];   // [1024,1024]
  float* out = (float*)d_out;                   // [2,2048,1024] fp32

  char* ws = (char*)d_ws;
  short* xb    = (short*)(ws);                    // 8 MB  [4096][1024] bf16
  short* wqkvT = (short*)(ws + (8u  << 20));      // 6 MB  [3072][1024] bf16
  short* woutT = (short*)(ws + (14u << 20));      // 2 MB  [1024][1024] bf16
  short* qbuf  = (short*)(ws + (16u << 20));      // 8 MB  [32][2048][64] bf16 (prescaled)
  short* kbuf  = (short*)(ws + (24u << 20));      // 8 MB  [32][2048][64] bf16
  short* vtbuf = (short*)(ws + (32u << 20));      // 8 MB  [32][64][2048] bf16 (V^T)
  short* obuf  = (short*)(ws + (40u << 20));      // 8 MB  [4096][1024] bf16

  cvt_kernel<<<2048, 256, 0, stream>>>(x, xb, (4096*1024)/4);
  transpose_cvt_kernel<<<dim3(96,32), 256, 0, stream>>>(w_qkv, wqkvT, 1024, 3072);
  transpose_cvt_kernel<<<dim3(32,32), 256, 0, stream>>>(w_out, woutT, 1024, 1024);

  gemm128_kernel<1><<<dim3(32,24), 256, 0, stream>>>(xb, wqkvT, nullptr,
                                                     qbuf, kbuf, vtbuf, 4096, 3072, 1024);
  attn_kernel<<<dim3(512), 512, 0, stream>>>(qbuf, kbuf, vtbuf, obuf);
  gemm128_kernel<0><<<dim3(32,8), 256, 0, stream>>>(obuf, woutT, out,
                                                    nullptr, nullptr, nullptr, 4096, 1024, 1024);
}

// Round 9
// 117.211 us; speedup vs baseline: 1.6261x; 1.0138x over previous
//
#include <hip/hip_runtime.h>

typedef float f32x4 __attribute__((ext_vector_type(4)));
typedef float f32x16 __attribute__((ext_vector_type(16)));
typedef short short8 __attribute__((ext_vector_type(8)));
typedef short short4_t __attribute__((ext_vector_type(4)));

#define GLOAD_LDS16(gp, lp) \
  __builtin_amdgcn_global_load_lds((const __attribute__((address_space(1))) void*)(gp), \
                                   (__attribute__((address_space(3))) void*)(lp), 16, 0, 0)

__device__ __forceinline__ short f2bf(float f){
  unsigned u = __builtin_bit_cast(unsigned, f);
  u += 0x7fffu + ((u >> 16) & 1u);   // RNE, no NaN inputs here
  return (short)(u >> 16);
}

__device__ __forceinline__ float exp2_fast(float x){
  return __builtin_amdgcn_exp2f(x);  // v_exp_f32: 2^x
}

// ---------------- fp32 -> bf16 convert (vectorized) ----------------
__global__ void cvt_kernel(const float* __restrict__ x, short* __restrict__ xb, int n4){
  for (int i = blockIdx.x*blockDim.x + threadIdx.x; i < n4; i += gridDim.x*blockDim.x){
    f32x4 v = ((const f32x4*)x)[i];
    short4_t s;
    s[0]=f2bf(v[0]); s[1]=f2bf(v[1]); s[2]=f2bf(v[2]); s[3]=f2bf(v[3]);
    ((short4_t*)xb)[i] = s;
  }
}

// ------------- transpose+convert: w[K][N] fp32 -> wT[N][K] bf16 -------------
__global__ __launch_bounds__(256) void transpose_cvt_kernel(const float* __restrict__ w,
                                                            short* __restrict__ wT,
                                                            int K, int N){
  __shared__ float tile[32][33];
  int bn = blockIdx.x*32, bk = blockIdx.y*32;
  int tx = threadIdx.x & 31, ty = threadIdx.x >> 5;   // 256 threads: ty 0..7
  #pragma unroll
  for (int r=ty; r<32; r+=8) tile[r][tx] = w[(size_t)(bk+r)*N + bn + tx];
  __syncthreads();
  #pragma unroll
  for (int r=ty; r<32; r+=8) wT[(size_t)(bn+r)*K + bk + tx] = f2bf(tile[tx][r]);
}

// ---------------- 128x128 bf16 GEMM: C = A[M][K] * Bt[N][K]^T ----------------
template<int MODE>
__global__ __launch_bounds__(256) void gemm128_kernel(
    const short* __restrict__ A, const short* __restrict__ Bt,
    float* __restrict__ Cf, short* __restrict__ qb_, short* __restrict__ kb_,
    short* __restrict__ vtb, int M, int N, int K)
{
  __shared__ short a_lds[128*64];
  __shared__ short b_lds[128*64];
  const int tid = threadIdx.x;
  const int lane = tid & 63;
  const int l15 = lane & 15, lg = lane >> 4;
  const int w  = tid >> 6;
  const int wr = w >> 1, wc = w & 1;
  const int m0 = blockIdx.x * 128, n0 = blockIdx.y * 128;

  f32x4 acc[4][4];
  #pragma unroll
  for (int i=0;i<4;i++)
    #pragma unroll
    for (int j=0;j<4;j++) acc[i][j] = (f32x4){0.f,0.f,0.f,0.f};

  for (int kt = 0; kt < K; kt += 64){
    __syncthreads();
    #pragma unroll
    for (int i=0;i<4;i++){
      int u = i*256 + tid;
      int row = u >> 3, cu = u & 7;
      int kl = ((cu ^ (row & 7)) << 3);
      GLOAD_LDS16(A + (size_t)(m0+row)*K + kt + kl, a_lds + (size_t)(i*256 + (tid & ~63))*8);
    }
    #pragma unroll
    for (int i=0;i<4;i++){
      int u = i*256 + tid;
      int row = u >> 3, cu = u & 7;
      int kl = ((cu ^ (row & 7)) << 3);
      GLOAD_LDS16(Bt + (size_t)(n0+row)*K + kt + kl, b_lds + (size_t)(i*256 + (tid & ~63))*8);
    }
    asm volatile("s_waitcnt vmcnt(0)" ::: "memory");
    __syncthreads();

    #pragma unroll
    for (int kk=0;kk<2;kk++){
      short8 af[4], bfr[4];
      #pragma unroll
      for (int mi=0;mi<4;mi++){
        int row = wr*64 + mi*16 + l15;
        int uu = ((kk*4 + lg) ^ (row & 7));
        af[mi] = *(const short8*)&a_lds[row*64 + uu*8];
      }
      #pragma unroll
      for (int ni=0;ni<4;ni++){
        int row = wc*64 + ni*16 + l15;
        int uu = ((kk*4 + lg) ^ (row & 7));
        bfr[ni] = *(const short8*)&b_lds[row*64 + uu*8];
      }
      #pragma unroll
      for (int mi=0;mi<4;mi++)
        #pragma unroll
        for (int ni=0;ni<4;ni++)
          acc[mi][ni] = __builtin_amdgcn_mfma_f32_16x16x32_bf16(af[mi], bfr[ni], acc[mi][ni], 0,0,0);
    }
  }

  // epilogue: D layout col = lane&15, row = (lane>>4)*4 + r  [verified m89/m91]
  #pragma unroll
  for (int mi=0;mi<4;mi++){
    #pragma unroll
    for (int ni=0;ni<4;ni++){
      int col = n0 + wc*64 + ni*16 + l15;
      #pragma unroll
      for (int r=0;r<4;r++){
        int rowg = m0 + wr*64 + mi*16 + lg*4 + r;
        float v = acc[mi][ni][r];
        if (MODE == 0){
          Cf[(size_t)rowg*N + col] = v;
        } else {
          int three = col >> 10, hh = (col >> 6) & 15, e = col & 63;
          int bb = rowg >> 11, t = rowg & 2047;
          int bh = bb*16 + hh;
          // Q pre-scale: 1/sqrt(64) * log2(e)  (softmax computed in base 2)
          if (three == 0)      qb_[((size_t)bh*2048 + t)*64 + e] = f2bf(v * (0.125f*1.44269504f));
          else if (three == 1) kb_[((size_t)bh*2048 + t)*64 + e] = f2bf(v);
          else                 vtb[((size_t)bh*64 + e)*2048 + t] = f2bf(v);          // V transposed
        }
      }
    }
  }
}

// ---------------- causal flash attention, 32x32 MFMA, P-in-register ----------------
// 256 threads = 4 waves, wave owns 32 q-rows (QBLK=128). KVBLK=128, dbuf, vmcnt(8).
// Swapped QK^T: sacc = mfma32(K, Q) = S^T; lane holds q = lane&31, 64 of 128 kv
// (partner lane+32 holds the rest). Softmax fully in-register (1 shfl_xor(32) per
// reduce). P -> PV A-frags via v_cvt_pk_bf16_f32 + v_permlane32_swap_b32 (no P-LDS).
// T13 defer-rescale (THR=8). T5 setprio around MFMA clusters.
__global__ __launch_bounds__(256) void attn_kernel(
    const short* __restrict__ q, const short* __restrict__ kbuf,
    const short* __restrict__ vt, short* __restrict__ ob)
{
  __shared__ short k_lds[2][128*64];      // [kv][k]
  __shared__ short v_lds[2][64*128];      // [d][kv] (V^T)

  const int tid = threadIdx.x, lane = tid & 63, w = tid >> 6;  // w 0..3
  const int l31 = lane & 31, hi = lane >> 5;
  const int qi = blockIdx.x >> 5;
  const int qb = (qi < 8) ? (15 - qi) : (qi - 8);   // paired blocks sum to 17 tiles
  const int bh = blockIdx.x & 31;
  const int q0 = qb * 128;

  // Q B-fragments (from global, once): q row = q0 + w*32 + l31; k = kk*16 + hi*8 + b
  const short* qg = q + ((size_t)bh*2048 + q0 + w*32 + l31)*64 + hi*8;
  short8 qf[4];
  #pragma unroll
  for (int kk=0;kk<4;kk++) qf[kk] = *(const short8*)(qg + kk*16);

  f32x16 o_acc[2];
  #pragma unroll
  for (int oc=0;oc<2;oc++)
    #pragma unroll
    for (int r=0;r<16;r++) o_acc[oc][r] = 0.f;
  float mreg = -1e30f, lreg = 0.f;        // per-lane: q = l31 (both halves identical)

  // LDS read offsets (bytes). K: row=ct*32+l31 (stride 128B), unit=(kk*2+hi)^(l31&7).
  // V: row=oc*32+l31 (stride 256B), unit=(ks*2+hi)^(l31&7).
  const int sw = l31 & 7;
  int kro[4], vro[8];
  #pragma unroll
  for (int kk=0;kk<4;kk++) kro[kk] = l31*128 + (((kk*2+hi)^sw) << 4);
  #pragma unroll
  for (int ks=0;ks<8;ks++) vro[ks] = l31*256 + (((ks*2+hi)^sw) << 4);

  // staging: 256 thr x (4 K + 4 V) gload_lds per tile; source pre-swizzled (Rule 21)
  const int xk = ((tid & 7) ^ ((tid >> 3) & 7)) * 8;
  const int xv = ((tid & 15) ^ ((tid >> 4) & 7)) * 8;
  const short* kp = kbuf + (size_t)bh*2048*64 + (size_t)(tid >> 3)*64 + xk;   // +8192/tile, +2048/i
  const short* vp = vt   + (size_t)bh*64*2048 + (size_t)(tid >> 4)*2048 + xv; // +128/tile,  +32768/i
  const int dst = (tid & ~63)*8;   // wave-uniform LDS dest base (shorts), +256*8/i

  const int n = qb + 1;
  #pragma unroll
  for (int i=0;i<4;i++) GLOAD_LDS16(kp + i*2048,  &k_lds[0][i*2048 + dst]);
  #pragma unroll
  for (int i=0;i<4;i++) GLOAD_LDS16(vp + i*32768, &v_lds[0][i*2048 + dst]);
  kp += 8192; vp += 128;

  for (int s = 0; s < n; s++){
    const int cur = s & 1;
    if (s + 1 < n){
      #pragma unroll
      for (int i=0;i<4;i++) GLOAD_LDS16(kp + i*2048,  &k_lds[cur^1][i*2048 + dst]);
      #pragma unroll
      for (int i=0;i<4;i++) GLOAD_LDS16(vp + i*32768, &v_lds[cur^1][i*2048 + dst]);
      kp += 8192; vp += 128;
      asm volatile("s_waitcnt vmcnt(8)" ::: "memory");  // tile s landed; s+1 in flight
    } else {
      asm volatile("s_waitcnt vmcnt(0)" ::: "memory");
    }
    __builtin_amdgcn_s_barrier();

    const char* kl_ = (const char*)&k_lds[cur][0];
    const char* vl_ = (const char*)&v_lds[cur][0];

    // QK^T: sacc[ct][r] = S^T[kv = s*128 + ct*32 + crow(r,hi)][q = l31]
    f32x16 sacc[4];
    #pragma unroll
    for (int ct=0;ct<4;ct++)
      #pragma unroll
      for (int r=0;r<16;r++) sacc[ct][r] = 0.f;
    __builtin_amdgcn_s_setprio(1);
    #pragma unroll
    for (int kk=0;kk<4;kk++){
      #pragma unroll
      for (int ct=0;ct<4;ct++){
        short8 kf = *(const short8*)(kl_ + kro[kk] + ct*4096);
        sacc[ct] = __builtin_amdgcn_mfma_f32_32x32x16_bf16(kf, qf[kk], sacc[ct], 0,0,0);
      }
    }
    __builtin_amdgcn_s_setprio(0);

    if (s == qb){   // diagonal tile: mask kv_local > q_local
      const int qloc = w*32 + l31 - 4*hi;
      #pragma unroll
      for (int ct=0;ct<4;ct++)
        #pragma unroll
        for (int r=0;r<16;r++)
          if (ct*32 + (r&3) + 8*(r>>2) > qloc) sacc[ct][r] = -1e30f;
    }

    // row max (64 in-lane values + partner half)
    float pmax = sacc[0][0];
    #pragma unroll
    for (int ct=0;ct<4;ct++)
      #pragma unroll
      for (int r=0;r<16;r++) pmax = fmaxf(pmax, sacc[ct][r]);
    pmax = fmaxf(pmax, __shfl_xor(pmax, 32));

    if (!__all(pmax - mreg <= 8.0f)){       // T13 defer-rescale
      float mnew = fmaxf(mreg, pmax);
      float alpha = exp2_fast(mreg - mnew);
      mreg = mnew;
      lreg *= alpha;
      float aRow[16];
      #pragma unroll
      for (int r=0;r<16;r++) aRow[r] = __shfl(alpha, (r&3) + 8*(r>>2) + 4*hi);
      #pragma unroll
      for (int oc=0;oc<2;oc++)
        #pragma unroll
        for (int r=0;r<16;r++) o_acc[oc][r] *= aRow[r];
    }

    // per ct: P = exp2(S - mreg), pack to bf16, build PV A-frags via permlane, MFMA
    float sum = 0.f;
    #pragma unroll
    for (int ct=0;ct<4;ct++){
      float pv[16];
      #pragma unroll
      for (int r=0;r<16;r++){ pv[r] = exp2_fast(sacc[ct][r] - mreg); sum += pv[r]; }
      unsigned pk[8];
      #pragma unroll
      for (int t=0;t<8;t++)
        asm("v_cvt_pk_bf16_f32 %0, %1, %2" : "=v"(pk[t]) : "v"(pv[2*t]), "v"(pv[2*t+1]));
      #pragma unroll
      for (int kss=0;kss<2;kss++){        // ks = 2*ct + kss
        const int W = 4*kss;
        unsigned x0 = pk[W],   x2 = pk[W+2];
        unsigned x1 = pk[W+1], x3 = pk[W+3];
        asm("v_permlane32_swap_b32 %0, %1" : "+v"(x0), "+v"(x2));
        asm("v_permlane32_swap_b32 %0, %1" : "+v"(x1), "+v"(x3));
        uint4 pau = {x0, x1, x2, x3};
        short8 pa = __builtin_bit_cast(short8, pau);
        __builtin_amdgcn_s_setprio(1);
        #pragma unroll
        for (int oc=0;oc<2;oc++){
          short8 vf = *(const short8*)(vl_ + vro[2*ct+kss] + oc*8192);
          o_acc[oc] = __builtin_amdgcn_mfma_f32_32x32x16_bf16(pa, vf, o_acc[oc], 0,0,0);
        }
        __builtin_amdgcn_s_setprio(0);
      }
    }
    sum += __shfl_xor(sum, 32);
    lreg += sum;

    __builtin_amdgcn_s_barrier();   // all reads of buf[cur] done before overwrite
  }

  // normalize + write O as bf16 row-major [b*t][h*64+e]; O row q = crow(r,hi), d = oc*32+l31
  const int bb = bh >> 4, hh = bh & 15;
  #pragma unroll
  for (int r=0;r<16;r++){
    float lf = __shfl(lreg, (r&3) + 8*(r>>2) + 4*hi);
    float inv = 1.0f / lf;
    int t = q0 + w*32 + (r&3) + 8*(r>>2) + 4*hi;
    size_t base = ((size_t)(bb*2048 + t))*1024 + (size_t)hh*64 + l31;
    ob[base]      = f2bf(o_acc[0][r] * inv);
    ob[base + 32] = f2bf(o_acc[1][r] * inv);
  }
}

extern "C" void kernel_launch(void* const* d_in, const int* in_sizes, int n_in,
                              void* d_out, int out_size, void* d_ws, size_t ws_size,
                              hipStream_t stream) {
  const float* x     = (const float*)d_in[0];   // [2,2048,1024]
  const float* w_qkv = (const float*)d_in[1];   // [1024,3072]
  const float* w_out = (const float*)d_in[2];   // [1024,1024]
  float* out = (float*)d_out;                   // [2,2048,1024] fp32

  char* ws = (char*)d_ws;
  short* xb    = (short*)(ws);                    // 8 MB  [4096][1024] bf16
  short* wqkvT = (short*)(ws + (8u  << 20));      // 6 MB  [3072][1024] bf16
  short* woutT = (short*)(ws + (14u << 20));      // 2 MB  [1024][1024] bf16
  short* qbuf  = (short*)(ws + (16u << 20));      // 8 MB  [32][2048][64] bf16 (prescaled)
  short* kbuf  = (short*)(ws + (24u << 20));      // 8 MB  [32][2048][64] bf16
  short* vtbuf = (short*)(ws + (32u << 20));      // 8 MB  [32][64][2048] bf16 (V^T)
  short* obuf  = (short*)(ws + (40u << 20));      // 8 MB  [4096][1024] bf16

  cvt_kernel<<<2048, 256, 0, stream>>>(x, xb, (4096*1024)/4);
  transpose_cvt_kernel<<<dim3(96,32), 256, 0, stream>>>(w_qkv, wqkvT, 1024, 3072);
  transpose_cvt_kernel<<<dim3(32,32), 256, 0, stream>>>(w_out, woutT, 1024, 1024);

  gemm128_kernel<1><<<dim3(32,24), 256, 0, stream>>>(xb, wqkvT, nullptr,
                                                     qbuf, kbuf, vtbuf, 4096, 3072, 1024);
  attn_kernel<<<dim3(512), 256, 0, stream>>>(qbuf, kbuf, vtbuf, obuf);
  gemm128_kernel<0><<<dim3(32,8), 256, 0, stream>>>(obuf, woutT, out,
                                                    nullptr, nullptr, nullptr, 4096, 1024, 1024);
}